// Round 5
// baseline (252.287 us; speedup 1.0000x reference)
//
#include <hip/hip_runtime.h>

// Backward bilinear warp, faithful to the reference's flat reinterpretation:
//   img2d  = image buffer viewed flat as (2B, M, N)
//   flow2[p] = flow[p/2]  (each batch's flow is used for BOTH pseudo-images
//              2b and 2b+1 — so one thread computes both outputs)
//   out flat = warped flat (2B, M, N) layout, reinterpreted as (B, M, N, 2)
__global__ __launch_bounds__(256) void warp_kernel(
    const float* __restrict__ image,   // flat, viewed as (2B, M, N)
    const float2* __restrict__ flow,   // (B, M, N) of float2 {dx, dy}
    float* __restrict__ out,           // flat, viewed as (2B, M, N)
    int totalBMN, int M, int N)
{
    int tid = blockIdx.x * blockDim.x + threadIdx.x;
    if (tid >= totalBMN) return;

    int x = tid % N;
    int t = tid / N;
    int y = t % M;
    int b = t / M;

    float2 f = flow[tid];
    float xs = (float)x + f.x;
    float ys = (float)y + f.y;

    float x0f = floorf(xs);
    float y0f = floorf(ys);
    float wx = xs - x0f;
    float wy = ys - y0f;
    int x0 = (int)x0f;
    int y0 = (int)y0f;
    int x1 = x0 + 1;
    int y1 = y0 + 1;

    float w00 = (1.0f - wy) * (1.0f - wx);
    float w01 = (1.0f - wy) * wx;
    float w10 = wy * (1.0f - wx);
    float w11 = wy * wx;

    // Per-corner validity; invalid corners contribute 0 (reference semantics:
    // clip-load then where(valid, v*w, 0) — loaded v is always finite, so
    // skipping the load is equivalent).
    bool xv0 = (x0 >= 0) & (x0 < N);
    bool xv1 = (x1 >= 0) & (x1 < N);
    bool yv0 = (y0 >= 0) & (y0 < M);
    bool yv1 = (y1 >= 0) & (y1 < M);

    int plane = M * N;
    const float* img0 = image + (2 * b) * plane;       // plane p = 2b
    const float* img1 = img0 + plane;                  // plane p = 2b+1

    float acc0 = 0.0f, acc1 = 0.0f;
    if (yv0) {
        int r0 = y0 * N;
        if (xv0) { acc0 += img0[r0 + x0] * w00; acc1 += img1[r0 + x0] * w00; }
        if (xv1) { acc0 += img0[r0 + x1] * w01; acc1 += img1[r0 + x1] * w01; }
    }
    if (yv1) {
        int r1 = y1 * N;
        if (xv0) { acc0 += img0[r1 + x0] * w10; acc1 += img1[r1 + x0] * w10; }
        if (xv1) { acc0 += img0[r1 + x1] * w11; acc1 += img1[r1 + x1] * w11; }
    }

    int o = y * N + x;
    out[(2 * b) * plane + o] = acc0;   // coalesced across x
    out[(2 * b + 1) * plane + o] = acc1;
}

extern "C" void kernel_launch(void* const* d_in, const int* in_sizes, int n_in,
                              void* d_out, int out_size, void* d_ws, size_t ws_size,
                              hipStream_t stream) {
    const float*  image = (const float*)d_in[0];   // (B, M, N, 2) f32
    const float2* flow  = (const float2*)d_in[1];  // (B, M, N, 2) f32 as float2
    float* out = (float*)d_out;                    // (B, M, N, 2) f32

    const int M = 384, N = 384;
    int B = in_sizes[0] / (M * N * 2);             // 64
    int totalBMN = B * M * N;                      // one thread per (b,y,x)

    int block = 256;
    int grid = (totalBMN + block - 1) / block;
    warp_kernel<<<grid, block, 0, stream>>>(image, flow, out, totalBMN, M, N);
}